// Round 13
// baseline (231.091 us; speedup 1.0000x reference)
//
#include <hip/hip_runtime.h>
#include <hip/hip_bf16.h>
#include <stdint.h>

#define NTOK 2048
#define NE 64
#define TOPK 4
#define DM 512
#define DF 2048
#define TOTSLOT (NTOK*TOPK)   // 8192

#define BM 192
#define BN 128
#define BK 64
#define GEMM_GRID 1024        // persistent stride grid

typedef __bf16 bf16;
typedef __bf16 bf16x8 __attribute__((ext_vector_type(8)));
typedef __bf16 bf16x4 __attribute__((ext_vector_type(4)));
typedef float  f32x4  __attribute__((ext_vector_type(4)));
typedef short  short8 __attribute__((ext_vector_type(8)));

// ---------------- routing: 2 kernels ----------------

__global__ void k_route(const float* __restrict__ hw, float* __restrict__ top_w,
                        int* __restrict__ top_idx) {
  int t = blockIdx.x * blockDim.x + threadIdx.x;
  if (t >= NTOK) return;
  const float* r = hw + (size_t)t * NE;
  float rv[NE];
  #pragma unroll
  for (int e = 0; e < NE; ++e) rv[e] = r[e];
  float v[TOPK]; int id[TOPK];
  #pragma unroll
  for (int k = 0; k < TOPK; ++k) {
    float best = -1e30f; int bi = 0;
    #pragma unroll
    for (int e = 0; e < NE; ++e) {
      bool used = false;
      #pragma unroll
      for (int j = 0; j < k; ++j) used |= (id[j] == e);
      if (!used && rv[e] > best) { best = rv[e]; bi = e; }
    }
    v[k] = best; id[k] = bi;
  }
  float den = v[0] + v[1] + v[2] + v[3] + 1e-8f;   // matches ref: sum + 1e-8
  #pragma unroll
  for (int k = 0; k < TOPK; ++k) {
    top_w[t*TOPK + k] = v[k] / den;
    top_idx[t*TOPK + k] = id[k];
  }
}

// 1 block: LDS histogram + shfl prefix scan + CSR fill (+ per-slot weight)
// + compact task list. tasklist entry = (e<<8)|mt; ntask_g = count.
__global__ __launch_bounds__(256) void k_build(
    const int* __restrict__ top_idx, const float* __restrict__ top_w,
    int* __restrict__ tok, float* __restrict__ wslot,
    int* __restrict__ slot_of, int* __restrict__ offsets_g,
    int* __restrict__ tasklist, int* __restrict__ ntask_g) {
  __shared__ int cnt_s[NE], off_s[NE + 1], fill_s[NE], tpre_s[NE + 1];
  const int tid = threadIdx.x;
  if (tid < NE) { cnt_s[tid] = 0; fill_s[tid] = 0; }
  __syncthreads();
  int ids[TOTSLOT / 256];
  #pragma unroll
  for (int c = 0; c < TOTSLOT / 256; ++c) {
    ids[c] = top_idx[c * 256 + tid];
    atomicAdd(&cnt_s[ids[c]], 1);
  }
  __syncthreads();
  if (tid < 64) {                       // wave 0: two exclusive prefix scans
    int c = cnt_s[tid];
    int inc = c;
    #pragma unroll
    for (int d = 1; d < 64; d <<= 1) {
      int n = __shfl_up(inc, d, 64);
      if (tid >= d) inc += n;
    }
    off_s[tid] = inc - c;
    if (tid == 63) off_s[64] = inc;

    int tc = (c + BM - 1) / BM;
    int tinc = tc;
    #pragma unroll
    for (int d = 1; d < 64; d <<= 1) {
      int n = __shfl_up(tinc, d, 64);
      if (tid >= d) tinc += n;
    }
    tpre_s[tid] = tinc - tc;
    if (tid == 63) tpre_s[64] = tinc;
  }
  __syncthreads();
  #pragma unroll
  for (int c = 0; c < TOTSLOT / 256; ++c) {
    int idx = c * 256 + tid;
    int e = ids[c];
    int pos = off_s[e] + atomicAdd(&fill_s[e], 1);
    tok[pos] = idx >> 2;                // token = idx / TOPK
    wslot[pos] = top_w[idx];            // per-slot combine weight
    slot_of[idx] = pos;
  }
  if (tid < 64) {
    int tc = (cnt_s[tid] + BM - 1) / BM;
    int base = tpre_s[tid];
    for (int m = 0; m < tc; ++m) tasklist[base + m] = (tid << 8) | m;
    if (tid == 0) *ntask_g = tpre_s[64];
  }
  if (tid <= NE) offsets_g[tid] = off_s[tid];
}

__global__ void k_xcast(const float* __restrict__ x, bf16* __restrict__ xb) {
  int i = blockIdx.x * blockDim.x + threadIdx.x;
  int base = i * 4;
  if (base >= NTOK * DM) return;
  float4 f = *(const float4*)(x + base);
  bf16x4 o;
  o[0] = (bf16)f.x; o[1] = (bf16)f.y; o[2] = (bf16)f.z; o[3] = (bf16)f.w;
  *(bf16x4*)(xb + base) = o;
}

// ---------------- grouped GEMM: R8 structure (measured best) ----------------
// Persistent compact tasks, simple 2-barrier inner loop (R2/R4/R9/R11/R12:
// no pipelining variant beat it). PASS2 fuses the combine: epilogue does
// atomicAdd(out[tok[slot]] , wslot[slot] * (acc + bias)) — eliminates the
// 64MB O-partial write + 64MB combine read + one launch. out is zeroed by
// hipMemsetAsync each call; fp atomic order jitter ~1e-6 << 3.1e-2 threshold.

template<int PASS, int KSPLIT>
__global__ __launch_bounds__(512) void k_gemm(
    const float* __restrict__ W, const float* __restrict__ bias,
    const bf16* __restrict__ Asrc, const int* __restrict__ tok,
    const float* __restrict__ wslot, const int* __restrict__ offsets,
    const int* __restrict__ tasklist, const int* __restrict__ ntask_g,
    bf16* __restrict__ Hout, float* __restrict__ out)
{
  constexpr int KFULL = (PASS == 1) ? DM : DF;
  constexpr int KLOC  = KFULL / KSPLIT;      // 512 both
  constexpr int KT    = KLOC / BK;           // 8 both
  constexpr int NDIM  = (PASS == 1) ? DF : DM;
  constexpr int NT    = NDIM / BN;           // 16 / 4
  constexpr int NTK   = NT * KSPLIT;         // 16 / 16

  const int tid = threadIdx.x;
  const int wave = tid >> 6, lane = tid & 63;
  const int wm = wave >> 1, wn = wave & 1;
  const int lrow = lane >> 4, lcol = lane & 15;

  __shared__ bf16 As[BM * BK];   // 24 KB
  __shared__ bf16 Bs[BN * BK];   // 16 KB

  const int tot = (*ntask_g) * NTK;

  #pragma unroll 1
  for (int tt = blockIdx.x; tt < tot; tt += GEMM_GRID) {
    const int emt   = tt / NTK;
    const int rest  = tt - emt * NTK;
    const int ntile = rest / KSPLIT;
    const int ks    = rest - ntile * KSPLIT;
    const int em    = tasklist[emt];
    const int e     = em >> 8;
    const int mt    = em & 255;
    const int kbase = ks * KLOC;

    const int off = offsets[e];
    const int cnt = offsets[e+1] - off;
    const int rowcount = cnt - mt * BM;      // r < rowcount guards validity

    // --- A staging map: 3 chunks x (512 thr x 8 bf16) covers 192x64 ---
    const bf16* abase[3]; bool aok[3];
    #pragma unroll
    for (int c = 0; c < 3; ++c) {
      int r = (c * 512 + tid) >> 3;
      aok[c] = (r < rowcount);
      int srcrow;
      if (PASS == 1) srcrow = aok[c] ? tok[off + mt*BM + r] : 0;
      else           srcrow = min(off + mt*BM + (aok[c] ? r : 0), TOTSLOT - 1);
      abase[c] = Asrc + (size_t)srcrow * KFULL + kbase + (tid & 7) * 8;
    }
    // --- B staging map: thread -> (row = tid>>2, 16-col segment) ---
    const int brow = tid >> 2;
    const float* bbase = W + (size_t)e * NDIM * KFULL
                           + (size_t)(ntile*BN + brow) * KFULL + kbase + (tid & 3) * 16;

    f32x4 acc[3][4];
    #pragma unroll
    for (int i = 0; i < 3; ++i)
      #pragma unroll
      for (int j = 0; j < 4; ++j) acc[i][j] = (f32x4)(0.0f);

    #pragma unroll 1
    for (int kt = 0; kt < KT; ++kt) {
      const int k0 = kt * BK;
      short8 areg[3];
      #pragma unroll
      for (int c = 0; c < 3; ++c) {
        if (PASS == 2 || aok[c]) areg[c] = *(const short8*)(abase[c] + k0);
        else                     areg[c] = (short8){0,0,0,0,0,0,0,0};
      }
      float4 breg[4];
      #pragma unroll
      for (int q = 0; q < 4; ++q) breg[q] = *(const float4*)(bbase + k0 + q*4);

      __syncthreads();   // previous tile fully consumed
      #pragma unroll
      for (int c = 0; c < 3; ++c) {
        int r = (c * 512 + tid) >> 3;
        int u = tid & 7;
        *(short8*)(&As[r*BK + ((u ^ (r & 7)) * 8)]) = areg[c];
      }
      {
        const float* fv = (const float*)breg;
        bf16x8 p0, p1;
        #pragma unroll
        for (int q = 0; q < 8; ++q) { p0[q] = (bf16)fv[q]; p1[q] = (bf16)fv[q+8]; }
        int u0 = (tid & 3) * 2;
        *(bf16x8*)(&Bs[brow*BK + (((u0  ) ^ (brow & 7)) * 8)]) = p0;
        *(bf16x8*)(&Bs[brow*BK + (((u0+1) ^ (brow & 7)) * 8)]) = p1;
      }
      __syncthreads();   // staging visible

      #pragma unroll
      for (int ksub = 0; ksub < 2; ++ksub) {
        const int uu = ksub*4 + lrow;
        bf16x8 af[3], bfr[4];
        #pragma unroll
        for (int i = 0; i < 3; ++i) {
          int m = wm*48 + i*16 + lcol;
          af[i] = *(const bf16x8*)(&As[m*BK + ((uu ^ (m & 7)) * 8)]);
        }
        #pragma unroll
        for (int j = 0; j < 4; ++j) {
          int n = wn*64 + j*16 + lcol;
          bfr[j] = *(const bf16x8*)(&Bs[n*BK + ((uu ^ (n & 7)) * 8)]);
        }
        #pragma unroll
        for (int i = 0; i < 3; ++i)
          #pragma unroll
          for (int j = 0; j < 4; ++j)
            acc[i][j] = __builtin_amdgcn_mfma_f32_16x16x32_bf16(af[i], bfr[j], acc[i][j], 0, 0, 0);
      }
    }

    // --- epilogue. C/D layout: col = lane&15, row = (lane>>4)*4 + reg ---
    const int slotbase = off + mt * BM;
    #pragma unroll
    for (int i = 0; i < 3; ++i) {
      const int rbase = wm*48 + i*16 + lrow*4;
      #pragma unroll
      for (int j = 0; j < 4; ++j) {
        const int gcol = ntile*BN + wn*64 + j*16 + lcol;
        const float bv = (PASS == 2 && ks != 0) ? 0.0f : bias[(size_t)e * NDIM + gcol];
        #pragma unroll
        for (int q = 0; q < 4; ++q) {
          const int r = rbase + q;
          if (r < rowcount) {
            float h = acc[i][j][q] + bv;
            if (PASS == 1) {
              float s = h / (1.0f + __expf(-h));      // silu
              Hout[(size_t)(slotbase + r) * DF + gcol] = (bf16)s;
            } else {
              const int slot = slotbase + r;
              atomicAdd(&out[(size_t)tok[slot] * DM + gcol], wslot[slot] * h);
            }
          }
        }
      }
    }
    __syncthreads();   // LDS reuse safety across tasks
  }
}

// ---------------- launch ----------------

extern "C" void kernel_launch(void* const* d_in, const int* in_sizes, int n_in,
                              void* d_out, int out_size, void* d_ws, size_t ws_size,
                              hipStream_t stream) {
  const float* x        = (const float*)d_in[0];
  const float* hw       = (const float*)d_in[1];
  const float* W_in     = (const float*)d_in[2];
  const float* bias_in  = (const float*)d_in[3];
  const float* W_out    = (const float*)d_in[4];
  const float* bias_out = (const float*)d_in[5];
  float* out = (float*)d_out;

  char* ws = (char*)d_ws;
  int*   offsets  = (int*)  (ws + 0);                    // 65 ints
  int*   ntask    = (int*)  (ws + 512);                  // 1 int
  int*   tasklist = (int*)  (ws + 768);                  // up to 128 ints
  int*   top_idx  = (int*)  (ws + 2048);                 // 32 KB
  float* top_w    = (float*)(ws + 2048 + 32768);         // 32 KB
  int*   slot_of  = (int*)  (ws + 2048 + 2*32768);       // 32 KB
  int*   tok      = (int*)  (ws + 2048 + 3*32768);       // 32 KB
  float* wslot    = (float*)(ws + 2048 + 4*32768);       // 32 KB
  bf16*  xb       = (bf16*) (ws + 2048 + 5*32768);       // 2 MB
  size_t o_xb_end = 2048 + 5*32768 + (size_t)NTOK*DM*2;
  bf16*  H        = (bf16*) (ws + o_xb_end);             // 32 MB

  k_route<<<NTOK/256, 256, 0, stream>>>(hw, top_w, top_idx);
  k_build<<<1, 256, 0, stream>>>(top_idx, top_w, tok, wslot, slot_of,
                                 offsets, tasklist, ntask);
  k_xcast<<<(NTOK*DM/4)/256, 256, 0, stream>>>(x, xb);
  hipMemsetAsync(d_out, 0, (size_t)out_size * sizeof(float), stream);

  k_gemm<1,1><<<GEMM_GRID, 512, 0, stream>>>(W_in, bias_in, xb, tok, nullptr,
                                             offsets, tasklist, ntask, H, nullptr);
  k_gemm<2,4><<<GEMM_GRID, 512, 0, stream>>>(W_out, bias_out, H, tok, wslot,
                                             offsets, tasklist, ntask, nullptr, out);
}

// Round 14
// 198.942 us; speedup vs baseline: 1.1616x; 1.1616x over previous
//
#include <hip/hip_runtime.h>
#include <hip/hip_bf16.h>
#include <stdint.h>

#define NTOK 2048
#define NE 64
#define TOPK 4
#define DM 512
#define DF 2048
#define TOTSLOT (NTOK*TOPK)   // 8192

#define BM 192
#define BN 128
#define BK 64
#define GEMM_GRID 1024        // persistent stride grid

typedef __bf16 bf16;
typedef __bf16 bf16x8 __attribute__((ext_vector_type(8)));
typedef __bf16 bf16x4 __attribute__((ext_vector_type(4)));
typedef float  f32x4  __attribute__((ext_vector_type(4)));
typedef short  short8 __attribute__((ext_vector_type(8)));

// ---------------- routing: 2 kernels ----------------

__global__ void k_route(const float* __restrict__ hw, float* __restrict__ top_w,
                        int* __restrict__ top_idx) {
  int t = blockIdx.x * blockDim.x + threadIdx.x;
  if (t >= NTOK) return;
  const float* r = hw + (size_t)t * NE;
  float rv[NE];
  #pragma unroll
  for (int e = 0; e < NE; ++e) rv[e] = r[e];
  float v[TOPK]; int id[TOPK];
  #pragma unroll
  for (int k = 0; k < TOPK; ++k) {
    float best = -1e30f; int bi = 0;
    #pragma unroll
    for (int e = 0; e < NE; ++e) {
      bool used = false;
      #pragma unroll
      for (int j = 0; j < k; ++j) used |= (id[j] == e);
      if (!used && rv[e] > best) { best = rv[e]; bi = e; }
    }
    v[k] = best; id[k] = bi;
  }
  float den = v[0] + v[1] + v[2] + v[3] + 1e-8f;   // matches ref: sum + 1e-8
  #pragma unroll
  for (int k = 0; k < TOPK; ++k) {
    top_w[t*TOPK + k] = v[k] / den;
    top_idx[t*TOPK + k] = id[k];
  }
}

// 1 block: LDS histogram + shfl prefix scan + CSR fill + compact task list.
__global__ __launch_bounds__(256) void k_build(
    const int* __restrict__ top_idx, int* __restrict__ tok,
    int* __restrict__ slot_of, int* __restrict__ offsets_g,
    int* __restrict__ tasklist, int* __restrict__ ntask_g) {
  __shared__ int cnt_s[NE], off_s[NE + 1], fill_s[NE], tpre_s[NE + 1];
  const int tid = threadIdx.x;
  if (tid < NE) { cnt_s[tid] = 0; fill_s[tid] = 0; }
  __syncthreads();
  int ids[TOTSLOT / 256];
  #pragma unroll
  for (int c = 0; c < TOTSLOT / 256; ++c) {
    ids[c] = top_idx[c * 256 + tid];
    atomicAdd(&cnt_s[ids[c]], 1);
  }
  __syncthreads();
  if (tid < 64) {                       // wave 0: two exclusive prefix scans
    int c = cnt_s[tid];
    int inc = c;
    #pragma unroll
    for (int d = 1; d < 64; d <<= 1) {
      int n = __shfl_up(inc, d, 64);
      if (tid >= d) inc += n;
    }
    off_s[tid] = inc - c;
    if (tid == 63) off_s[64] = inc;

    int tc = (c + BM - 1) / BM;
    int tinc = tc;
    #pragma unroll
    for (int d = 1; d < 64; d <<= 1) {
      int n = __shfl_up(tinc, d, 64);
      if (tid >= d) tinc += n;
    }
    tpre_s[tid] = tinc - tc;
    if (tid == 63) tpre_s[64] = tinc;
  }
  __syncthreads();
  #pragma unroll
  for (int c = 0; c < TOTSLOT / 256; ++c) {
    int idx = c * 256 + tid;
    int e = ids[c];
    int pos = off_s[e] + atomicAdd(&fill_s[e], 1);
    tok[pos] = idx >> 2;                // token = idx / TOPK
    slot_of[idx] = pos;
  }
  if (tid < 64) {
    int tc = (cnt_s[tid] + BM - 1) / BM;
    int base = tpre_s[tid];
    for (int m = 0; m < tc; ++m) tasklist[base + m] = (tid << 8) | m;
    if (tid == 0) *ntask_g = tpre_s[64];
  }
  if (tid <= NE) offsets_g[tid] = off_s[tid];
}

__global__ void k_xcast(const float* __restrict__ x, bf16* __restrict__ xb) {
  int i = blockIdx.x * blockDim.x + threadIdx.x;
  int base = i * 4;
  if (base >= NTOK * DM) return;
  float4 f = *(const float4*)(x + base);
  bf16x4 o;
  o[0] = (bf16)f.x; o[1] = (bf16)f.y; o[2] = (bf16)f.z; o[3] = (bf16)f.w;
  *(bf16x4*)(xb + base) = o;
}

// ---------------- grouped GEMM: R8 structure (measured best) ----------------
// Persistent compact tasks; simple 2-barrier inner loop (R2/3/4/5/9/11/12:
// nothing beat it). PASS2: KSPLIT=2 (vs R8's 4) — O-partial traffic scales
// with KSPLIT while H re-reads depend only on NT, so this halves O traffic
// (128->64MB) at identical H traffic. 544 units -> ~2.1 blocks/CU (the
// documented minimum for barrier-drain overlap).

template<int PASS, int KSPLIT>
__global__ __launch_bounds__(512) void k_gemm(
    const float* __restrict__ W, const float* __restrict__ bias,
    const bf16* __restrict__ Asrc, const int* __restrict__ tok,
    const int* __restrict__ offsets,
    const int* __restrict__ tasklist, const int* __restrict__ ntask_g,
    bf16* __restrict__ Hout, float* __restrict__ Oout)
{
  constexpr int KFULL = (PASS == 1) ? DM : DF;
  constexpr int KLOC  = KFULL / KSPLIT;      // 512 / 1024
  constexpr int KT    = KLOC / BK;           // 8 / 16
  constexpr int NDIM  = (PASS == 1) ? DF : DM;
  constexpr int NT    = NDIM / BN;           // 16 / 4
  constexpr int NTK   = NT * KSPLIT;         // 16 / 8

  const int tid = threadIdx.x;
  const int wave = tid >> 6, lane = tid & 63;
  const int wm = wave >> 1, wn = wave & 1;
  const int lrow = lane >> 4, lcol = lane & 15;

  __shared__ bf16 As[BM * BK];   // 24 KB
  __shared__ bf16 Bs[BN * BK];   // 16 KB

  const int tot = (*ntask_g) * NTK;

  #pragma unroll 1
  for (int tt = blockIdx.x; tt < tot; tt += GEMM_GRID) {
    const int emt   = tt / NTK;
    const int rest  = tt - emt * NTK;
    const int ntile = rest / KSPLIT;
    const int ks    = rest - ntile * KSPLIT;
    const int em    = tasklist[emt];
    const int e     = em >> 8;
    const int mt    = em & 255;
    const int kbase = ks * KLOC;

    const int off = offsets[e];
    const int cnt = offsets[e+1] - off;
    const int rowcount = cnt - mt * BM;      // r < rowcount guards validity

    // --- A staging map: 3 chunks x (512 thr x 8 bf16) covers 192x64 ---
    const bf16* abase[3]; bool aok[3];
    #pragma unroll
    for (int c = 0; c < 3; ++c) {
      int r = (c * 512 + tid) >> 3;
      aok[c] = (r < rowcount);
      int srcrow;
      if (PASS == 1) srcrow = aok[c] ? tok[off + mt*BM + r] : 0;
      else           srcrow = min(off + mt*BM + (aok[c] ? r : 0), TOTSLOT - 1);
      abase[c] = Asrc + (size_t)srcrow * KFULL + kbase + (tid & 7) * 8;
    }
    // --- B staging map: thread -> (row = tid>>2, 16-col segment) ---
    const int brow = tid >> 2;
    const float* bbase = W + (size_t)e * NDIM * KFULL
                           + (size_t)(ntile*BN + brow) * KFULL + kbase + (tid & 3) * 16;

    f32x4 acc[3][4];
    #pragma unroll
    for (int i = 0; i < 3; ++i)
      #pragma unroll
      for (int j = 0; j < 4; ++j) acc[i][j] = (f32x4)(0.0f);

    #pragma unroll 1
    for (int kt = 0; kt < KT; ++kt) {
      const int k0 = kt * BK;
      short8 areg[3];
      #pragma unroll
      for (int c = 0; c < 3; ++c) {
        if (PASS == 2 || aok[c]) areg[c] = *(const short8*)(abase[c] + k0);
        else                     areg[c] = (short8){0,0,0,0,0,0,0,0};
      }
      float4 breg[4];
      #pragma unroll
      for (int q = 0; q < 4; ++q) breg[q] = *(const float4*)(bbase + k0 + q*4);

      __syncthreads();   // previous tile fully consumed
      #pragma unroll
      for (int c = 0; c < 3; ++c) {
        int r = (c * 512 + tid) >> 3;
        int u = tid & 7;
        *(short8*)(&As[r*BK + ((u ^ (r & 7)) * 8)]) = areg[c];
      }
      {
        const float* fv = (const float*)breg;
        bf16x8 p0, p1;
        #pragma unroll
        for (int q = 0; q < 8; ++q) { p0[q] = (bf16)fv[q]; p1[q] = (bf16)fv[q+8]; }
        int u0 = (tid & 3) * 2;
        *(bf16x8*)(&Bs[brow*BK + (((u0  ) ^ (brow & 7)) * 8)]) = p0;
        *(bf16x8*)(&Bs[brow*BK + (((u0+1) ^ (brow & 7)) * 8)]) = p1;
      }
      __syncthreads();   // staging visible

      #pragma unroll
      for (int ksub = 0; ksub < 2; ++ksub) {
        const int uu = ksub*4 + lrow;
        bf16x8 af[3], bfr[4];
        #pragma unroll
        for (int i = 0; i < 3; ++i) {
          int m = wm*48 + i*16 + lcol;
          af[i] = *(const bf16x8*)(&As[m*BK + ((uu ^ (m & 7)) * 8)]);
        }
        #pragma unroll
        for (int j = 0; j < 4; ++j) {
          int n = wn*64 + j*16 + lcol;
          bfr[j] = *(const bf16x8*)(&Bs[n*BK + ((uu ^ (n & 7)) * 8)]);
        }
        #pragma unroll
        for (int i = 0; i < 3; ++i)
          #pragma unroll
          for (int j = 0; j < 4; ++j)
            acc[i][j] = __builtin_amdgcn_mfma_f32_16x16x32_bf16(af[i], bfr[j], acc[i][j], 0, 0, 0);
      }
    }

    // --- epilogue. C/D layout: col = lane&15, row = (lane>>4)*4 + reg ---
    const int slotbase = off + mt * BM;
    #pragma unroll
    for (int i = 0; i < 3; ++i) {
      const int rbase = wm*48 + i*16 + lrow*4;
      #pragma unroll
      for (int j = 0; j < 4; ++j) {
        const int gcol = ntile*BN + wn*64 + j*16 + lcol;
        const float bv = (PASS == 2 && ks != 0) ? 0.0f : bias[(size_t)e * NDIM + gcol];
        #pragma unroll
        for (int q = 0; q < 4; ++q) {
          const int r = rbase + q;
          if (r < rowcount) {
            float h = acc[i][j][q] + bv;
            if (PASS == 1) {
              float s = h / (1.0f + __expf(-h));      // silu
              Hout[(size_t)(slotbase + r) * DF + gcol] = (bf16)s;
            } else {
              Oout[(size_t)ks * TOTSLOT * DM + (size_t)(slotbase + r) * DM + gcol] = h;
            }
          }
        }
      }
    }
    __syncthreads();   // LDS reuse safety across tasks
  }
}

// ---------------- combine (deterministic, sums 2 K-split partials) ----------------

__global__ void k_combine(const float* __restrict__ O, const float* __restrict__ top_w,
                          const int* __restrict__ slot_of, float* __restrict__ out) {
  int i = blockIdx.x * blockDim.x + threadIdx.x;
  if (i >= NTOK * DM / 4) return;
  int t  = i / (DM / 4);
  int d4 = (i % (DM / 4)) * 4;
  float4 s = {0.f, 0.f, 0.f, 0.f};
  #pragma unroll
  for (int k = 0; k < TOPK; ++k) {
    float w = top_w[t*TOPK + k];
    int  sl = slot_of[t*TOPK + k];
    float4 o0 = *(const float4*)(O + (size_t)sl * DM + d4);
    float4 o1 = *(const float4*)(O + (size_t)TOTSLOT * DM + (size_t)sl * DM + d4);
    s.x += w * (o0.x + o1.x); s.y += w * (o0.y + o1.y);
    s.z += w * (o0.z + o1.z); s.w += w * (o0.w + o1.w);
  }
  *(float4*)(out + (size_t)t * DM + d4) = s;
}

// ---------------- launch ----------------

extern "C" void kernel_launch(void* const* d_in, const int* in_sizes, int n_in,
                              void* d_out, int out_size, void* d_ws, size_t ws_size,
                              hipStream_t stream) {
  const float* x        = (const float*)d_in[0];
  const float* hw       = (const float*)d_in[1];
  const float* W_in     = (const float*)d_in[2];
  const float* bias_in  = (const float*)d_in[3];
  const float* W_out    = (const float*)d_in[4];
  const float* bias_out = (const float*)d_in[5];
  float* out = (float*)d_out;

  char* ws = (char*)d_ws;
  int*   offsets  = (int*)  (ws + 0);                    // 65 ints
  int*   ntask    = (int*)  (ws + 512);                  // 1 int
  int*   tasklist = (int*)  (ws + 768);                  // up to 128 ints
  int*   top_idx  = (int*)  (ws + 2048);                 // 32 KB
  float* top_w    = (float*)(ws + 2048 + 32768);         // 32 KB
  int*   slot_of  = (int*)  (ws + 2048 + 2*32768);       // 32 KB
  int*   tok      = (int*)  (ws + 2048 + 3*32768);       // 32 KB
  bf16*  xb       = (bf16*) (ws + 2048 + 4*32768);       // 2 MB
  size_t o_xb_end = 2048 + 4*32768 + (size_t)NTOK*DM*2;
  bf16*  H        = (bf16*) (ws + o_xb_end);             // 32 MB
  size_t o_H_end  = o_xb_end + (size_t)TOTSLOT*DF*2;
  float* O        = (float*)(ws + o_H_end);              // 2 x 16 MB partials

  k_route<<<NTOK/256, 256, 0, stream>>>(hw, top_w, top_idx);
  k_build<<<1, 256, 0, stream>>>(top_idx, tok, slot_of, offsets, tasklist, ntask);
  k_xcast<<<(NTOK*DM/4)/256, 256, 0, stream>>>(x, xb);

  k_gemm<1,1><<<GEMM_GRID, 512, 0, stream>>>(W_in, bias_in, xb, tok, offsets,
                                             tasklist, ntask, H, nullptr);
  k_gemm<2,2><<<GEMM_GRID, 512, 0, stream>>>(W_out, bias_out, H, nullptr, offsets,
                                             tasklist, ntask, nullptr, O);

  k_combine<<<(NTOK*DM/4)/256, 256, 0, stream>>>(O, top_w, slot_of, out);
}

// Round 16
// 189.052 us; speedup vs baseline: 1.2224x; 1.0523x over previous
//
#include <hip/hip_runtime.h>
#include <hip/hip_bf16.h>
#include <stdint.h>

#define NTOK 2048
#define NE 64
#define TOPK 4
#define DM 512
#define DF 2048
#define TOTSLOT (NTOK*TOPK)   // 8192

#define BM 192
#define BN 128
#define BK 64
#define GEMM_GRID 1024        // persistent stride grid

typedef __bf16 bf16;
typedef __bf16 bf16x8 __attribute__((ext_vector_type(8)));
typedef __bf16 bf16x4 __attribute__((ext_vector_type(4)));
typedef float  f32x4  __attribute__((ext_vector_type(4)));
typedef short  short8 __attribute__((ext_vector_type(8)));

// ---------------- routing + xcast fused ----------------
// 64 blocks x 256: threads with gid < NTOK do per-token top-4 routing;
// ALL threads grid-stride the x fp32->bf16 cast.
// NTOK*DM/4 = 262144 float4 units / 16384 threads = 16 iterations (R15 bug: was 4).

__global__ __launch_bounds__(256) void k_routecast(
    const float* __restrict__ hw, const float* __restrict__ x,
    float* __restrict__ top_w, int* __restrict__ top_idx,
    bf16* __restrict__ xb) {
  const int gid = blockIdx.x * blockDim.x + threadIdx.x;   // 0..16383
  if (gid < NTOK) {
    const int t = gid;
    const float* r = hw + (size_t)t * NE;
    float rv[NE];
    #pragma unroll
    for (int e = 0; e < NE; ++e) rv[e] = r[e];
    float v[TOPK]; int id[TOPK];
    #pragma unroll
    for (int k = 0; k < TOPK; ++k) {
      float best = -1e30f; int bi = 0;
      #pragma unroll
      for (int e = 0; e < NE; ++e) {
        bool used = false;
        #pragma unroll
        for (int j = 0; j < k; ++j) used |= (id[j] == e);
        if (!used && rv[e] > best) { best = rv[e]; bi = e; }
      }
      v[k] = best; id[k] = bi;
    }
    float den = v[0] + v[1] + v[2] + v[3] + 1e-8f;   // matches ref: sum + 1e-8
    #pragma unroll
    for (int k = 0; k < TOPK; ++k) {
      top_w[t*TOPK + k] = v[k] / den;
      top_idx[t*TOPK + k] = id[k];
    }
  }
  // grid-stride xcast: 262144 float4 units over 16384 threads = 16 iters
  #pragma unroll
  for (int c = 0; c < 16; ++c) {
    int i = c * 16384 + gid;
    int base = i * 4;
    float4 f = *(const float4*)(x + base);
    bf16x4 o;
    o[0] = (bf16)f.x; o[1] = (bf16)f.y; o[2] = (bf16)f.z; o[3] = (bf16)f.w;
    *(bf16x4*)(xb + base) = o;
  }
}

// 1 block: LDS histogram + shfl prefix scan + CSR fill + compact task list.
__global__ __launch_bounds__(256) void k_build(
    const int* __restrict__ top_idx, int* __restrict__ tok,
    int* __restrict__ slot_of, int* __restrict__ offsets_g,
    int* __restrict__ tasklist, int* __restrict__ ntask_g) {
  __shared__ int cnt_s[NE], off_s[NE + 1], fill_s[NE], tpre_s[NE + 1];
  const int tid = threadIdx.x;
  if (tid < NE) { cnt_s[tid] = 0; fill_s[tid] = 0; }
  __syncthreads();
  int ids[TOTSLOT / 256];
  #pragma unroll
  for (int c = 0; c < TOTSLOT / 256; ++c) {
    ids[c] = top_idx[c * 256 + tid];
    atomicAdd(&cnt_s[ids[c]], 1);
  }
  __syncthreads();
  if (tid < 64) {                       // wave 0: two exclusive prefix scans
    int c = cnt_s[tid];
    int inc = c;
    #pragma unroll
    for (int d = 1; d < 64; d <<= 1) {
      int n = __shfl_up(inc, d, 64);
      if (tid >= d) inc += n;
    }
    off_s[tid] = inc - c;
    if (tid == 63) off_s[64] = inc;

    int tc = (c + BM - 1) / BM;
    int tinc = tc;
    #pragma unroll
    for (int d = 1; d < 64; d <<= 1) {
      int n = __shfl_up(tinc, d, 64);
      if (tid >= d) tinc += n;
    }
    tpre_s[tid] = tinc - tc;
    if (tid == 63) tpre_s[64] = tinc;
  }
  __syncthreads();
  #pragma unroll
  for (int c = 0; c < TOTSLOT / 256; ++c) {
    int idx = c * 256 + tid;
    int e = ids[c];
    int pos = off_s[e] + atomicAdd(&fill_s[e], 1);
    tok[pos] = idx >> 2;                // token = idx / TOPK
    slot_of[idx] = pos;
  }
  if (tid < 64) {
    int tc = (cnt_s[tid] + BM - 1) / BM;
    int base = tpre_s[tid];
    for (int m = 0; m < tc; ++m) tasklist[base + m] = (tid << 8) | m;
    if (tid == 0) *ntask_g = tpre_s[64];
  }
  if (tid <= NE) offsets_g[tid] = off_s[tid];
}

// ---------------- grouped GEMM: R8/R14 structure (measured best) ----------------
// Persistent compact tasks; simple 2-barrier inner loop (R2/3/4/5/9/11/12:
// nothing beat it). PASS2: KSPLIT=4 (1024 units = 4 blocks/CU, R8's best
// occupancy) with O partials stored as BF16 (4 x 8MB = same bytes as R14's
// fp32 x2, at higher occupancy). Partial magnitude ~O(1), bf16 err ~0.004.

template<int PASS, int KSPLIT>
__global__ __launch_bounds__(512) void k_gemm(
    const float* __restrict__ W, const float* __restrict__ bias,
    const bf16* __restrict__ Asrc, const int* __restrict__ tok,
    const int* __restrict__ offsets,
    const int* __restrict__ tasklist, const int* __restrict__ ntask_g,
    bf16* __restrict__ Hout, bf16* __restrict__ Oout)
{
  constexpr int KFULL = (PASS == 1) ? DM : DF;
  constexpr int KLOC  = KFULL / KSPLIT;      // 512 both
  constexpr int KT    = KLOC / BK;           // 8 both
  constexpr int NDIM  = (PASS == 1) ? DF : DM;
  constexpr int NT    = NDIM / BN;           // 16 / 4
  constexpr int NTK   = NT * KSPLIT;         // 16 / 16

  const int tid = threadIdx.x;
  const int wave = tid >> 6, lane = tid & 63;
  const int wm = wave >> 1, wn = wave & 1;
  const int lrow = lane >> 4, lcol = lane & 15;

  __shared__ bf16 As[BM * BK];   // 24 KB
  __shared__ bf16 Bs[BN * BK];   // 16 KB

  const int tot = (*ntask_g) * NTK;

  #pragma unroll 1
  for (int tt = blockIdx.x; tt < tot; tt += GEMM_GRID) {
    const int emt   = tt / NTK;
    const int rest  = tt - emt * NTK;
    const int ntile = rest / KSPLIT;
    const int ks    = rest - ntile * KSPLIT;
    const int em    = tasklist[emt];
    const int e     = em >> 8;
    const int mt    = em & 255;
    const int kbase = ks * KLOC;

    const int off = offsets[e];
    const int cnt = offsets[e+1] - off;
    const int rowcount = cnt - mt * BM;      // r < rowcount guards validity

    // --- A staging map: 3 chunks x (512 thr x 8 bf16) covers 192x64 ---
    const bf16* abase[3]; bool aok[3];
    #pragma unroll
    for (int c = 0; c < 3; ++c) {
      int r = (c * 512 + tid) >> 3;
      aok[c] = (r < rowcount);
      int srcrow;
      if (PASS == 1) srcrow = aok[c] ? tok[off + mt*BM + r] : 0;
      else           srcrow = min(off + mt*BM + (aok[c] ? r : 0), TOTSLOT - 1);
      abase[c] = Asrc + (size_t)srcrow * KFULL + kbase + (tid & 7) * 8;
    }
    // --- B staging map: thread -> (row = tid>>2, 16-col segment) ---
    const int brow = tid >> 2;
    const float* bbase = W + (size_t)e * NDIM * KFULL
                           + (size_t)(ntile*BN + brow) * KFULL + kbase + (tid & 3) * 16;

    f32x4 acc[3][4];
    #pragma unroll
    for (int i = 0; i < 3; ++i)
      #pragma unroll
      for (int j = 0; j < 4; ++j) acc[i][j] = (f32x4)(0.0f);

    #pragma unroll 1
    for (int kt = 0; kt < KT; ++kt) {
      const int k0 = kt * BK;
      short8 areg[3];
      #pragma unroll
      for (int c = 0; c < 3; ++c) {
        if (PASS == 2 || aok[c]) areg[c] = *(const short8*)(abase[c] + k0);
        else                     areg[c] = (short8){0,0,0,0,0,0,0,0};
      }
      float4 breg[4];
      #pragma unroll
      for (int q = 0; q < 4; ++q) breg[q] = *(const float4*)(bbase + k0 + q*4);

      __syncthreads();   // previous tile fully consumed
      #pragma unroll
      for (int c = 0; c < 3; ++c) {
        int r = (c * 512 + tid) >> 3;
        int u = tid & 7;
        *(short8*)(&As[r*BK + ((u ^ (r & 7)) * 8)]) = areg[c];
      }
      {
        const float* fv = (const float*)breg;
        bf16x8 p0, p1;
        #pragma unroll
        for (int q = 0; q < 8; ++q) { p0[q] = (bf16)fv[q]; p1[q] = (bf16)fv[q+8]; }
        int u0 = (tid & 3) * 2;
        *(bf16x8*)(&Bs[brow*BK + (((u0  ) ^ (brow & 7)) * 8)]) = p0;
        *(bf16x8*)(&Bs[brow*BK + (((u0+1) ^ (brow & 7)) * 8)]) = p1;
      }
      __syncthreads();   // staging visible

      #pragma unroll
      for (int ksub = 0; ksub < 2; ++ksub) {
        const int uu = ksub*4 + lrow;
        bf16x8 af[3], bfr[4];
        #pragma unroll
        for (int i = 0; i < 3; ++i) {
          int m = wm*48 + i*16 + lcol;
          af[i] = *(const bf16x8*)(&As[m*BK + ((uu ^ (m & 7)) * 8)]);
        }
        #pragma unroll
        for (int j = 0; j < 4; ++j) {
          int n = wn*64 + j*16 + lcol;
          bfr[j] = *(const bf16x8*)(&Bs[n*BK + ((uu ^ (n & 7)) * 8)]);
        }
        #pragma unroll
        for (int i = 0; i < 3; ++i)
          #pragma unroll
          for (int j = 0; j < 4; ++j)
            acc[i][j] = __builtin_amdgcn_mfma_f32_16x16x32_bf16(af[i], bfr[j], acc[i][j], 0, 0, 0);
      }
    }

    // --- epilogue. C/D layout: col = lane&15, row = (lane>>4)*4 + reg ---
    const int slotbase = off + mt * BM;
    #pragma unroll
    for (int i = 0; i < 3; ++i) {
      const int rbase = wm*48 + i*16 + lrow*4;
      #pragma unroll
      for (int j = 0; j < 4; ++j) {
        const int gcol = ntile*BN + wn*64 + j*16 + lcol;
        const float bv = (PASS == 2 && ks != 0) ? 0.0f : bias[(size_t)e * NDIM + gcol];
        #pragma unroll
        for (int q = 0; q < 4; ++q) {
          const int r = rbase + q;
          if (r < rowcount) {
            float h = acc[i][j][q] + bv;
            if (PASS == 1) {
              float s = h / (1.0f + __expf(-h));      // silu
              Hout[(size_t)(slotbase + r) * DF + gcol] = (bf16)s;
            } else {
              Oout[(size_t)ks * TOTSLOT * DM + (size_t)(slotbase + r) * DM + gcol] = (bf16)h;
            }
          }
        }
      }
    }
    __syncthreads();   // LDS reuse safety across tasks
  }
}

// ---------------- combine (deterministic, sums 4 bf16 K-split partials) ----------------

__global__ void k_combine(const bf16* __restrict__ O, const float* __restrict__ top_w,
                          const int* __restrict__ slot_of, float* __restrict__ out) {
  int i = blockIdx.x * blockDim.x + threadIdx.x;
  if (i >= NTOK * DM / 4) return;
  int t  = i / (DM / 4);
  int d4 = (i % (DM / 4)) * 4;
  float4 s = {0.f, 0.f, 0.f, 0.f};
  #pragma unroll
  for (int k = 0; k < TOPK; ++k) {
    float w = top_w[t*TOPK + k];
    int  sl = slot_of[t*TOPK + k];
    float sx = 0.f, sy = 0.f, sz = 0.f, sw = 0.f;
    #pragma unroll
    for (int p = 0; p < 4; ++p) {
      bf16x4 o = *(const bf16x4*)(O + (size_t)p * TOTSLOT * DM + (size_t)sl * DM + d4);
      sx += (float)o[0]; sy += (float)o[1]; sz += (float)o[2]; sw += (float)o[3];
    }
    s.x += w * sx; s.y += w * sy; s.z += w * sz; s.w += w * sw;
  }
  *(float4*)(out + (size_t)t * DM + d4) = s;
}

// ---------------- launch ----------------

extern "C" void kernel_launch(void* const* d_in, const int* in_sizes, int n_in,
                              void* d_out, int out_size, void* d_ws, size_t ws_size,
                              hipStream_t stream) {
  const float* x        = (const float*)d_in[0];
  const float* hw       = (const float*)d_in[1];
  const float* W_in     = (const float*)d_in[2];
  const float* bias_in  = (const float*)d_in[3];
  const float* W_out    = (const float*)d_in[4];
  const float* bias_out = (const float*)d_in[5];
  float* out = (float*)d_out;

  char* ws = (char*)d_ws;
  int*   offsets  = (int*)  (ws + 0);                    // 65 ints
  int*   ntask    = (int*)  (ws + 512);                  // 1 int
  int*   tasklist = (int*)  (ws + 768);                  // up to 128 ints
  int*   top_idx  = (int*)  (ws + 2048);                 // 32 KB
  float* top_w    = (float*)(ws + 2048 + 32768);         // 32 KB
  int*   slot_of  = (int*)  (ws + 2048 + 2*32768);       // 32 KB
  int*   tok      = (int*)  (ws + 2048 + 3*32768);       // 32 KB
  bf16*  xb       = (bf16*) (ws + 2048 + 4*32768);       // 2 MB
  size_t o_xb_end = 2048 + 4*32768 + (size_t)NTOK*DM*2;
  bf16*  H        = (bf16*) (ws + o_xb_end);             // 32 MB
  size_t o_H_end  = o_xb_end + (size_t)TOTSLOT*DF*2;
  bf16*  O        = (bf16*) (ws + o_H_end);              // 4 x 8 MB bf16 partials

  k_routecast<<<64, 256, 0, stream>>>(hw, x, top_w, top_idx, xb);
  k_build<<<1, 256, 0, stream>>>(top_idx, tok, slot_of, offsets, tasklist, ntask);

  k_gemm<1,1><<<GEMM_GRID, 512, 0, stream>>>(W_in, bias_in, xb, tok, offsets,
                                             tasklist, ntask, H, nullptr);
  k_gemm<2,4><<<GEMM_GRID, 512, 0, stream>>>(W_out, bias_out, H, nullptr, offsets,
                                             tasklist, ntask, nullptr, O);

  k_combine<<<(NTOK*DM/4)/256, 256, 0, stream>>>(O, top_w, slot_of, out);
}